// Round 4
// baseline (1398.331 us; speedup 1.0000x reference)
//
#include <hip/hip_runtime.h>
#include <hip/hip_bf16.h>

typedef __attribute__((ext_vector_type(8))) __bf16 bf16x8;
typedef __attribute__((ext_vector_type(4))) float f32x4;

#define ACT_NONE 0
#define ACT_RELU 1
#define ACT_GELU 2
#define ACT_TANH 3
#define OUT_F32 0
#define OUT_BF16 1
#define OUT_ADD 2
#define OUT_ATOMIC 3

#define LDST 40  // LDS row stride (elems): 80B = 5x16B -> b128-aligned, 2-way bank alias (free)

// ---------------- implicit-GEMM A addressing ----------------
// MODE 0: plain row-major A[M][K]
// MODE 1: conv1 im2col: input (1920,84,84,4) f32, 8x8 s4 -> k=ky*32+(kx*4+ci)
// MODE 2: conv2 im2col: input (1920,20,20,32), 4x4 s2 -> k=(ky*4+kx)*32+ci
// MODE 3: conv3 im2col: input (1920,9,9,64),  3x3 s1 -> k=(ky*3+kx)*64+ci
template<int MODE, int K>
__device__ __forceinline__ size_t a_rowbase(int m) {
  if constexpr (MODE == 0) {
    return (size_t)m * K;
  } else if constexpr (MODE == 1) {
    int img = m / 400; int p = m - img * 400; int oy = p / 20; int ox = p - oy * 20;
    return (size_t)img * 28224 + oy * 1344 + ox * 16;
  } else if constexpr (MODE == 2) {
    int img = m / 81; int p = m - img * 81; int oy = p / 9; int ox = p - oy * 9;
    return (size_t)img * 12800 + oy * 1280 + ox * 64;
  } else {
    int img = m / 49; int p = m - img * 49; int oy = p / 7; int ox = p - oy * 7;
    return (size_t)img * 5184 + oy * 576 + ox * 64;
  }
}
// k-offset within a row; chunks of 8 never cross a contiguous run boundary
template<int MODE>
__device__ __forceinline__ int a_koff(int k) {
  if constexpr (MODE == 0) return k;
  else if constexpr (MODE == 1) return (k >> 5) * 336 + (k & 31);
  else if constexpr (MODE == 2) return (k >> 7) * 640 + ((k >> 5) & 3) * 32 + (k & 31);
  else { int ky = k / 192; int r = k - ky * 192; return ky * 576 + r; }
}

__device__ __forceinline__ bf16x8 ld8f(const float* f) {
  float4 a = *(const float4*)f;
  float4 b = *(const float4*)(f + 4);
  bf16x8 r;
  r[0] = (__bf16)a.x; r[1] = (__bf16)a.y; r[2] = (__bf16)a.z; r[3] = (__bf16)a.w;
  r[4] = (__bf16)b.x; r[5] = (__bf16)b.y; r[6] = (__bf16)b.z; r[7] = (__bf16)b.w;
  return r;
}

__device__ __forceinline__ float act_apply(float v, int ACT) {
  if (ACT == ACT_RELU) return fmaxf(v, 0.f);
  if (ACT == ACT_GELU) return 0.5f * v * (1.f + erff(v * 0.70710678118f));
  if (ACT == ACT_TANH) return tanhf(v);
  return v;
}

// ---------------- generic MFMA GEMM:  C[M][N] (+)= act(A * BT^T + bias) ----------------
// Register double-buffered staging (prefetch next k-tile during MFMA), LDS stride 40.
// Tile TM x TN, BK=32, 4 waves as WM x WN. Optional split-K (NSPLIT) with atomic epilogue.
template<int MODE, int TM, int TN, int WM, int WN, int K, int ACT, int OUTM, int LDC, int NSPLIT>
__global__ __launch_bounds__(256) void gemm_rs(const __bf16* __restrict__ A,
                                               const __bf16* __restrict__ BT,
                                               const float* __restrict__ bias,
                                               void* __restrict__ C) {
  constexpr int SM = TM / WM, SN = TN / WN;
  constexpr int AM = SM / 16, AN = SN / 16;
  constexpr int CA = TM / 64, CB = TN / 64;  // 8-elem chunks per thread
  constexpr int KS = K / NSPLIT;
  __shared__ __align__(16) __bf16 As[TM * LDST];
  __shared__ __align__(16) __bf16 Bs[TN * LDST];
  const int tid = threadIdx.x;
  const int wave = tid >> 6, lane = tid & 63;
  const int quad = lane >> 4, l16 = lane & 15;
  const int wr = wave % WM, wc = wave / WM;
  const int m0 = blockIdx.x * TM, n0 = blockIdx.y * TN;
  const int ks0 = blockIdx.z * KS;

  size_t abase[CA]; int akc[CA], alds[CA];
  const __bf16* bptr[CB]; int blds[CB];
#pragma unroll
  for (int t = 0; t < CA; ++t) {
    const int idx = tid + 256 * t, r = idx >> 2, kc = (idx & 3) * 8;
    abase[t] = a_rowbase<MODE, K>(m0 + r);
    akc[t] = kc;
    alds[t] = r * LDST + kc;
  }
#pragma unroll
  for (int t = 0; t < CB; ++t) {
    const int idx = tid + 256 * t, r = idx >> 2, kc = (idx & 3) * 8;
    bptr[t] = BT + (size_t)(n0 + r) * K + ks0 + kc;
    blds[t] = r * LDST + kc;
  }

  f32x4 acc[AM][AN] = {};
  bf16x8 av[CA], bvv[CB];
#pragma unroll
  for (int t = 0; t < CA; ++t)
    av[t] = *(const bf16x8*)(A + abase[t] + a_koff<MODE>(ks0 + akc[t]));
#pragma unroll
  for (int t = 0; t < CB; ++t)
    bvv[t] = *(const bf16x8*)bptr[t];

  constexpr int NK = KS / 32;
  for (int kt = 0; kt < NK; ++kt) {
    __syncthreads();
#pragma unroll
    for (int t = 0; t < CA; ++t) *(bf16x8*)&As[alds[t]] = av[t];
#pragma unroll
    for (int t = 0; t < CB; ++t) *(bf16x8*)&Bs[blds[t]] = bvv[t];
    __syncthreads();
    if (kt + 1 < NK) {
      const int kb = (kt + 1) * 32;
#pragma unroll
      for (int t = 0; t < CA; ++t)
        av[t] = *(const bf16x8*)(A + abase[t] + a_koff<MODE>(ks0 + kb + akc[t]));
#pragma unroll
      for (int t = 0; t < CB; ++t)
        bvv[t] = *(const bf16x8*)(bptr[t] + kb);
    }
    bf16x8 af[AM], bf[AN];
#pragma unroll
    for (int mt = 0; mt < AM; ++mt)
      af[mt] = *(const bf16x8*)&As[(wr * SM + mt * 16 + l16) * LDST + quad * 8];
#pragma unroll
    for (int nt = 0; nt < AN; ++nt)
      bf[nt] = *(const bf16x8*)&Bs[(wc * SN + nt * 16 + l16) * LDST + quad * 8];
#pragma unroll
    for (int mt = 0; mt < AM; ++mt)
#pragma unroll
      for (int nt = 0; nt < AN; ++nt)
        acc[mt][nt] = __builtin_amdgcn_mfma_f32_16x16x32_bf16(af[mt], bf[nt], acc[mt][nt], 0, 0, 0);
  }

  // epilogue: C/D layout col=lane&15, row=quad*4+reg
#pragma unroll
  for (int nt = 0; nt < AN; ++nt) {
    const int col = n0 + wc * SN + nt * 16 + l16;
    const float bvl = (NSPLIT == 1 || blockIdx.z == 0) ? bias[col] : 0.f;
#pragma unroll
    for (int mt = 0; mt < AM; ++mt) {
#pragma unroll
      for (int r = 0; r < 4; ++r) {
        const int row = m0 + wr * SM + mt * 16 + quad * 4 + r;
        float v = act_apply(acc[mt][nt][r] + bvl, ACT);
        const size_t off = (size_t)row * LDC + col;
        if constexpr (OUTM == OUT_F32) ((float*)C)[off] = v;
        else if constexpr (OUTM == OUT_BF16) ((__bf16*)C)[off] = (__bf16)v;
        else if constexpr (OUTM == OUT_ADD) ((float*)C)[off] += v;
        else atomicAdd(&((float*)C)[off], v);
      }
    }
  }
}

// ---------------- conv1: f32 A (im2col MODE 1), 128x32 tile, K=256, register-staged ----------------
__global__ __launch_bounds__(256) void conv1_k(const float* __restrict__ A,
                                               const __bf16* __restrict__ BT,
                                               const float* __restrict__ bias,
                                               __bf16* __restrict__ C) {
  __shared__ __align__(16) __bf16 As[128 * LDST];
  __shared__ __align__(16) __bf16 Bs[32 * LDST];
  const int tid = threadIdx.x;
  const int wave = tid >> 6, lane = tid & 63;
  const int quad = lane >> 4, l16 = lane & 15;
  const int m0 = blockIdx.x * 128;
  const int r0 = tid >> 2, k0o = (tid & 3) * 8;  // A rows r0, r0+64
  const int r1 = r0 + 64;
  const size_t ar0 = a_rowbase<1, 256>(m0 + r0);
  const size_t ar1 = a_rowbase<1, 256>(m0 + r1);
  const __bf16* bp = BT + (size_t)r0 * 256 + k0o;  // valid for tid<128 (rows 0..31)

  f32x4 acc[2][2] = {};
  bf16x8 a0 = ld8f(A + ar0 + k0o);
  bf16x8 a1 = ld8f(A + ar1 + k0o);
  bf16x8 b0;
  if (tid < 128) b0 = *(const bf16x8*)bp;
  for (int kt = 0; kt < 8; ++kt) {
    __syncthreads();
    *(bf16x8*)&As[r0 * LDST + k0o] = a0;
    *(bf16x8*)&As[r1 * LDST + k0o] = a1;
    if (tid < 128) *(bf16x8*)&Bs[r0 * LDST + k0o] = b0;
    __syncthreads();
    if (kt < 7) {
      const int fa = (kt + 1) * 336;  // f32 k-offset (ky stride 336 floats)
      a0 = ld8f(A + ar0 + fa + k0o);
      a1 = ld8f(A + ar1 + fa + k0o);
      if (tid < 128) b0 = *(const bf16x8*)(bp + (kt + 1) * 32);
    }
    bf16x8 af[2], bf[2];
#pragma unroll
    for (int mt = 0; mt < 2; ++mt)
      af[mt] = *(const bf16x8*)&As[(wave * 32 + mt * 16 + l16) * LDST + quad * 8];
#pragma unroll
    for (int nt = 0; nt < 2; ++nt)
      bf[nt] = *(const bf16x8*)&Bs[(nt * 16 + l16) * LDST + quad * 8];
#pragma unroll
    for (int mt = 0; mt < 2; ++mt)
#pragma unroll
      for (int nt = 0; nt < 2; ++nt)
        acc[mt][nt] = __builtin_amdgcn_mfma_f32_16x16x32_bf16(af[mt], bf[nt], acc[mt][nt], 0, 0, 0);
  }
#pragma unroll
  for (int nt = 0; nt < 2; ++nt) {
    const int col = nt * 16 + l16;
    const float bvl = bias[col];
#pragma unroll
    for (int mt = 0; mt < 2; ++mt) {
#pragma unroll
      for (int r = 0; r < 4; ++r) {
        const int row = m0 + wave * 32 + mt * 16 + quad * 4 + r;
        C[(size_t)row * 32 + col] = (__bf16)fmaxf(acc[mt][nt][r] + bvl, 0.f);
      }
    }
  }
}

// ---------------- one-shot prep: all weight transposes (f32 -> bf16 BT layout) + bias concat ----------------
__device__ __forceinline__ void tp32(const float* __restrict__ src, __bf16* __restrict__ dst,
                                     int R, int C, int bx, int by, float scale, float (*t)[33]) {
  const int tid = threadIdx.x;
  const int tx = tid & 31, ty = tid >> 5;
  const int r0 = bx * 32, c0 = by * 32;
  for (int i = ty; i < 32; i += 8) {
    int r = r0 + i, c = c0 + tx;
    t[i][tx] = (r < R && c < C) ? src[(size_t)r * C + c] : 0.f;
  }
  __syncthreads();
  for (int i = ty; i < 32; i += 8) {
    int c = c0 + i, r = r0 + tx;
    if (c < C && r < R) dst[(size_t)c * R + r] = (__bf16)(t[tx][i] * scale);
  }
}

__global__ void prep_k(const float* conv1_w, const float* conv2_w, const float* conv3_w,
                       const float* dense_s_w, const float* Wk, const float* Wq, const float* Wv,
                       const float* W1, const float* W2, const float* W_head,
                       const float* bk, const float* bq, const float* bv,
                       __bf16* c1wT, __bf16* c2wT, __bf16* c3wT, __bf16* dswT,
                       __bf16* qkvT, __bf16* w1T, __bf16* w2T, __bf16* whT, float* bqkv) {
  __shared__ float t[32][33];
  int b = blockIdx.x;
  if (b < 8) { tp32(conv1_w, c1wT, 256, 32, b, 0, 1.f / 255.f, t); return; }
  b -= 8;
  if (b < 32) { tp32(conv2_w, c2wT, 512, 64, b >> 1, b & 1, 1.f, t); return; }
  b -= 32;
  if (b < 36) { tp32(conv3_w, c3wT, 576, 64, b >> 1, b & 1, 1.f, t); return; }
  b -= 36;
  if (b < 1568) { tp32(dense_s_w, dswT, 3136, 512, b >> 4, b & 15, 1.f, t); return; }
  b -= 1568;
  if (b < 4608) {  // Wk/Wq/Wv: 6 layers x 256 blocks each group
    const int g = b >> 11, rem = b & 2047;  // g in 0..2 -> k,q,v  (2048 > 1536 ok? no!)
    // 1536 blocks per group: decode manually
    const int gb = b / 1536, r2 = b - gb * 1536;
    const float* srcs[3] = {Wk, Wq, Wv};
    const int z = r2 >> 8, r3 = r2 & 255;
    tp32(srcs[gb] + (size_t)z * 262144, qkvT + (size_t)z * 786432 + (size_t)gb * 262144,
         512, 512, r3 >> 4, r3 & 15, 1.f, t);
    (void)g; (void)rem;
    return;
  }
  b -= 4608;
  if (b < 6144) {  // W1: 6 x 1024 blocks (512x2048 -> 16x64 tiles)
    const int z = b >> 10, r3 = b & 1023;
    tp32(W1 + (size_t)z * 1048576, w1T + (size_t)z * 1048576, 512, 2048, r3 >> 6, r3 & 63, 1.f, t);
    return;
  }
  b -= 6144;
  if (b < 6144) {  // W2: 6 x 1024 blocks (2048x512 -> 64x16 tiles)
    const int z = b >> 10, r3 = b & 1023;
    tp32(W2 + (size_t)z * 1048576, w2T + (size_t)z * 1048576, 2048, 512, r3 >> 4, r3 & 15, 1.f, t);
    return;
  }
  b -= 6144;
  if (b < 16) { tp32(W_head, whT, 512, 18, b, 0, 1.f, t); return; }
  b -= 16;
  // bias concat: bqkv[z*1536 + d]
  for (int idx = threadIdx.x; idx < 9216; idx += 256) {
    const int z = idx / 1536, d = idx - z * 1536;
    float v;
    if (d < 512) v = bk[z * 512 + d];
    else if (d < 1024) v = bq[z * 512 + d - 512];
    else v = bv[z * 512 + d - 1024];
    bqkv[idx] = v;
  }
}

// ---------------- token embedding: x = interleave(rtg_e, st_e, a_e) + pos ----------------
__global__ void embed_k(const float* __restrict__ rtgs, const int* __restrict__ actions,
                        const int* __restrict__ timesteps, const float* __restrict__ W_rtg,
                        const float* __restrict__ b_rtg, const float* __restrict__ emb_a,
                        const float* __restrict__ abs_pos, const float* __restrict__ rel_pos,
                        const float* __restrict__ ste, float* __restrict__ x) {
  const int idx = blockIdx.x * 256 + threadIdx.x;  // 64*90*512 total
  const int d = idx & 511; const int rb = idx >> 9;
  const int b = rb / 90, t = rb - b * 90;
  const int l = t / 3, r = t - l * 3;
  const float pos = rel_pos[t * 512 + d] + abs_pos[(size_t)timesteps[b] * 512 + d];
  float tok;
  if (r == 0) tok = tanhf(rtgs[b * 30 + l] * W_rtg[d] + b_rtg[d]);
  else if (r == 1) tok = ste[(size_t)(b * 30 + l) * 512 + d];
  else tok = tanhf(emb_a[actions[b * 30 + l] * 512 + d]);
  x[idx] = tok + pos;
}

// ---------------- layernorm: h_bf16 = LN(x_f32) * g + b, one wave per row ----------------
__global__ __launch_bounds__(256) void ln_k(const float* __restrict__ x, const float* __restrict__ g,
                                            const float* __restrict__ bb, __bf16* __restrict__ h) {
  const int row = blockIdx.x * 4 + (threadIdx.x >> 6);
  const int lane = threadIdx.x & 63;
  const float* xr = x + (size_t)row * 512;
  float4 a = *(const float4*)&xr[lane * 8];
  float4 c = *(const float4*)&xr[lane * 8 + 4];
  float vv[8] = {a.x, a.y, a.z, a.w, c.x, c.y, c.z, c.w};
  float s = 0.f, q = 0.f;
#pragma unroll
  for (int j = 0; j < 8; ++j) { s += vv[j]; q += vv[j] * vv[j]; }
  for (int o = 32; o; o >>= 1) { s += __shfl_xor(s, o); q += __shfl_xor(q, o); }
  const float mean = s * (1.f / 512.f);
  const float var = q * (1.f / 512.f) - mean * mean;
  const float rstd = rsqrtf(var + 1e-3f);
  float4 g1 = *(const float4*)&g[lane * 8];
  float4 g2 = *(const float4*)&g[lane * 8 + 4];
  float4 b1 = *(const float4*)&bb[lane * 8];
  float4 b2 = *(const float4*)&bb[lane * 8 + 4];
  float gg[8] = {g1.x, g1.y, g1.z, g1.w, g2.x, g2.y, g2.z, g2.w};
  float bbv[8] = {b1.x, b1.y, b1.z, b1.w, b2.x, b2.y, b2.z, b2.w};
  bf16x8 ov;
#pragma unroll
  for (int j = 0; j < 8; ++j)
    ov[j] = (__bf16)((vv[j] - mean) * rstd * gg[j] + bbv[j]);
  *(bf16x8*)&h[(size_t)row * 512 + lane * 8] = ov;
}

// ---------------- fused attention per (b,h): s=K@Q^T/8 masked, softmax, o=W@V, x += o ----------------
__global__ __launch_bounds__(256) void attn_k(const __bf16* __restrict__ qkv, float* __restrict__ x) {
  __shared__ __align__(16) char smem[64512];
  __bf16* kS = (__bf16*)smem;              // [96][72]  13824B
  __bf16* qS = (__bf16*)(smem + 13824);    // [96][72]  13824B
  __bf16* wS = (__bf16*)smem;              // [96][104] 19968B (reuses k/q after scores)
  float* sS = (float*)(smem + 27648);      // [96][96]  36864B
  __bf16* vT = (__bf16*)(smem + 27648);    // [64][104] 13312B (reuses sS after softmax)

  const int tid = threadIdx.x;
  const int b = blockIdx.x >> 3, h = blockIdx.x & 7;
  const int wave = tid >> 6, lane = tid & 63, quad = lane >> 4, l16 = lane & 15;
  const size_t rowbase = (size_t)b * 90 * 1536 + h * 64;

  for (int c = tid; c < 768; c += 256) {
    const int t = c >> 3, d8 = (c & 7) * 8;
    bf16x8 kv, qv;
#pragma unroll
    for (int j = 0; j < 8; ++j) { kv[j] = (__bf16)0.f; qv[j] = (__bf16)0.f; }
    if (t < 90) {
      const __bf16* src = qkv + rowbase + (size_t)t * 1536 + d8;
      kv = *(const bf16x8*)src;
      qv = *(const bf16x8*)(src + 512);
    }
    *(bf16x8*)&kS[t * 72 + d8] = kv;
    *(bf16x8*)&qS[t * 72 + d8] = qv;
  }
  __syncthreads();

  for (int tt = wave; tt < 36; tt += 4) {
    const int it = tt / 6, jt = tt - it * 6;
    f32x4 acc = {0.f, 0.f, 0.f, 0.f};
#pragma unroll
    for (int ks = 0; ks < 2; ++ks) {
      bf16x8 af = *(const bf16x8*)&kS[(it * 16 + l16) * 72 + ks * 32 + quad * 8];
      bf16x8 bq = *(const bf16x8*)&qS[(jt * 16 + l16) * 72 + ks * 32 + quad * 8];
      acc = __builtin_amdgcn_mfma_f32_16x16x32_bf16(af, bq, acc, 0, 0, 0);
    }
    const int col = jt * 16 + l16;
#pragma unroll
    for (int r = 0; r < 4; ++r) {
      const int row = it * 16 + quad * 4 + r;
      sS[row * 96 + col] = (col <= row && col < 90) ? acc[r] * 0.125f : -1e30f;
    }
  }
  __syncthreads();

  for (int row = wave; row < 96; row += 4) {
    const float e0 = sS[row * 96 + lane];
    const float e1 = (lane < 32) ? sS[row * 96 + 64 + lane] : -1e30f;
    float m = fmaxf(e0, e1);
    for (int o = 32; o; o >>= 1) m = fmaxf(m, __shfl_xor(m, o));
    const float p0 = __expf(e0 - m);
    const float p1 = (lane < 32) ? __expf(e1 - m) : 0.f;
    float s = p0 + p1;
    for (int o = 32; o; o >>= 1) s += __shfl_xor(s, o);
    const float inv = 1.f / s;
    wS[row * 104 + lane] = (__bf16)(p0 * inv);
    if (lane < 32) wS[row * 104 + 64 + lane] = (__bf16)(p1 * inv);
  }
  __syncthreads();

  for (int c = tid; c < 768; c += 256) {
    const int t = c >> 3, d8 = (c & 7) * 8;
    bf16x8 vv;
#pragma unroll
    for (int j = 0; j < 8; ++j) vv[j] = (__bf16)0.f;
    if (t < 90) vv = *(const bf16x8*)(qkv + rowbase + (size_t)t * 1536 + 1024 + d8);
#pragma unroll
    for (int j = 0; j < 8; ++j) vT[(d8 + j) * 104 + t] = vv[j];
  }
  __syncthreads();

  for (int tt = wave; tt < 24; tt += 4) {
    const int it = tt >> 2, dt = tt & 3;
    f32x4 acc = {0.f, 0.f, 0.f, 0.f};
#pragma unroll
    for (int ks = 0; ks < 3; ++ks) {
      bf16x8 aw = *(const bf16x8*)&wS[(it * 16 + l16) * 104 + ks * 32 + quad * 8];
      bf16x8 bv = *(const bf16x8*)&vT[(dt * 16 + l16) * 104 + ks * 32 + quad * 8];
      acc = __builtin_amdgcn_mfma_f32_16x16x32_bf16(aw, bv, acc, 0, 0, 0);
    }
    const int d = dt * 16 + l16;
#pragma unroll
    for (int r = 0; r < 4; ++r) {
      const int i = it * 16 + quad * 4 + r;
      if (i < 90) {
        float* p = x + (size_t)(b * 90 + i) * 512 + h * 64 + d;
        *p += acc[r];
      }
    }
  }
}

// ---------------- fused final LN + head (state tokens only), 1 wave per output row ----------------
__global__ __launch_bounds__(64) void head_k(const float* __restrict__ x, const float* __restrict__ g,
                                             const float* __restrict__ bb, const __bf16* __restrict__ whT,
                                             float* __restrict__ out) {
  const int m = blockIdx.x;  // 0..1919 = b*30+l
  const int b = m / 30, l = m - b * 30;
  const float* xr = x + (size_t)(b * 90 + 3 * l + 1) * 512;
  const int lane = threadIdx.x;
  float4 a = *(const float4*)&xr[lane * 8];
  float4 c = *(const float4*)&xr[lane * 8 + 4];
  float vv[8] = {a.x, a.y, a.z, a.w, c.x, c.y, c.z, c.w};
  float s = 0.f, q = 0.f;
#pragma unroll
  for (int j = 0; j < 8; ++j) { s += vv[j]; q += vv[j] * vv[j]; }
  for (int o = 32; o; o >>= 1) { s += __shfl_xor(s, o); q += __shfl_xor(q, o); }
  const float mean = s * (1.f / 512.f);
  const float var = q * (1.f / 512.f) - mean * mean;
  const float rstd = rsqrtf(var + 1e-3f);
  float4 g1 = *(const float4*)&g[lane * 8];
  float4 g2 = *(const float4*)&g[lane * 8 + 4];
  float4 b1 = *(const float4*)&bb[lane * 8];
  float4 b2 = *(const float4*)&bb[lane * 8 + 4];
  float gg[8] = {g1.x, g1.y, g1.z, g1.w, g2.x, g2.y, g2.z, g2.w};
  float bbv[8] = {b1.x, b1.y, b1.z, b1.w, b2.x, b2.y, b2.z, b2.w};
#pragma unroll
  for (int j = 0; j < 8; ++j)
    vv[j] = (vv[j] - mean) * rstd * gg[j] + bbv[j];
  for (int aa = 0; aa < 18; ++aa) {
    bf16x8 w = *(const bf16x8*)&whT[aa * 512 + lane * 8];
    float d = 0.f;
#pragma unroll
    for (int j = 0; j < 8; ++j) d += vv[j] * (float)w[j];
    for (int o = 32; o; o >>= 1) d += __shfl_xor(d, o);
    if (lane == 0) out[m * 18 + aa] = d;
  }
}

// ---------------- host ----------------
extern "C" void kernel_launch(void* const* d_in, const int* in_sizes, int n_in,
                              void* d_out, int out_size, void* d_ws, size_t ws_size,
                              hipStream_t stream) {
  const float* rtgs = (const float*)d_in[0];
  const float* states = (const float*)d_in[1];
  const int* actions = (const int*)d_in[2];
  const int* timesteps = (const int*)d_in[3];
  const float* W_rtg = (const float*)d_in[4];
  const float* b_rtg = (const float*)d_in[5];
  const float* conv1_w = (const float*)d_in[6];
  const float* conv1_b = (const float*)d_in[7];
  const float* conv2_w = (const float*)d_in[8];
  const float* conv2_b = (const float*)d_in[9];
  const float* conv3_w = (const float*)d_in[10];
  const float* conv3_b = (const float*)d_in[11];
  const float* dense_s_w = (const float*)d_in[12];
  const float* dense_s_b = (const float*)d_in[13];
  const float* emb_a = (const float*)d_in[14];
  const float* abs_pos = (const float*)d_in[15];
  const float* rel_pos = (const float*)d_in[16];
  const float* ln1_g = (const float*)d_in[17];
  const float* ln1_b = (const float*)d_in[18];
  const float* Wk = (const float*)d_in[19];
  const float* bk = (const float*)d_in[20];
  const float* Wq = (const float*)d_in[21];
  const float* bq = (const float*)d_in[22];
  const float* Wv = (const float*)d_in[23];
  const float* bv = (const float*)d_in[24];
  const float* ln2_g = (const float*)d_in[25];
  const float* ln2_b = (const float*)d_in[26];
  const float* W1 = (const float*)d_in[27];
  const float* b1 = (const float*)d_in[28];
  const float* W2 = (const float*)d_in[29];
  const float* b2 = (const float*)d_in[30];
  const float* lnf_g = (const float*)d_in[31];
  const float* lnf_b = (const float*)d_in[32];
  const float* W_head = (const float*)d_in[33];
  float* out = (float*)d_out;

  // workspace layout (bytes); transient region aliases dead buffers
  char* W = (char*)d_ws;
  float* x = (float*)(W + 0);                   // 5760*512 f32      11,796,480
  __bf16* h = (__bf16*)(W + 11796480);          // 5760*512 bf16      5,898,240
  __bf16* qkvT = (__bf16*)(W + 17694720);       // 6*1536*512 bf16    9,437,184
  __bf16* w1T = (__bf16*)(W + 27131904);        // 6*2048*512 bf16   12,582,912
  __bf16* w2T = (__bf16*)(W + 39714816);        // 6*512*2048 bf16   12,582,912
  __bf16* dswT = (__bf16*)(W + 52297728);       // 512*3136 bf16      3,211,264
  __bf16* c1wT = (__bf16*)(W + 55508992);       // 32*256 bf16
  __bf16* c2wT = (__bf16*)(W + 55574528);       // 64*512 bf16
  __bf16* c3wT = (__bf16*)(W + 55705600);       // 64*576 bf16
  __bf16* whT = (__bf16*)(W + 55853056);        // 18*512 bf16
  float* bqkv = (float*)(W + 55889920);         // 6*1536 f32
  // transient region base = 55,926,784
  __bf16* c1out = (__bf16*)(W + 55926784);      // 768000*32 bf16    49,152,000
  __bf16* c2out = (__bf16*)(W + 105078784);     // 155520*64 bf16    19,906,560
  __bf16* c3out = (__bf16*)(W + 55926784);      // 94080*64 bf16     (aliases dead c1out)
  float* ste = (float*)(W + 67969024);          // 1920*512 f32      (after c3out)
  __bf16* qkvb = (__bf16*)(W + 55926784);       // 5760*1536 bf16    (aliases dead conv bufs)
  __bf16* mlph = (__bf16*)(W + 73621504);       // 5760*2048 bf16
  // end = 124,985,344 bytes

  // one-shot weight prep: 8+32+36+1568+4608+6144+6144+16+1 = 18557 blocks
  prep_k<<<18557, 256, 0, stream>>>(conv1_w, conv2_w, conv3_w, dense_s_w, Wk, Wq, Wv, W1, W2,
                                    W_head, bk, bq, bv, c1wT, c2wT, c3wT, dswT, qkvT, w1T, w2T,
                                    whT, bqkv);

  // conv stem as implicit GEMM + dense embedding
  conv1_k<<<6000, 256, 0, stream>>>(states, c1wT, conv1_b, c1out);
  gemm_rs<2, 128, 64, 2, 2, 512, ACT_RELU, OUT_BF16, 64, 1><<<dim3(1215, 1), 256, 0, stream>>>(
      c1out, c2wT, conv2_b, c2out);
  gemm_rs<3, 128, 64, 2, 2, 576, ACT_RELU, OUT_BF16, 64, 1><<<dim3(735, 1), 256, 0, stream>>>(
      c2out, c3wT, conv3_b, c3out);
  gemm_rs<0, 64, 64, 2, 2, 3136, ACT_TANH, OUT_F32, 512, 1><<<dim3(30, 8), 256, 0, stream>>>(
      c3out, dswT, dense_s_b, (void*)ste);

  embed_k<<<11520, 256, 0, stream>>>(rtgs, actions, timesteps, W_rtg, b_rtg, emb_a, abs_pos, rel_pos, ste, x);

  for (int i = 0; i < 6; ++i) {
    ln_k<<<1440, 256, 0, stream>>>(x, ln1_g + i * 512, ln1_b + i * 512, h);
    gemm_rs<0, 128, 128, 2, 2, 512, ACT_NONE, OUT_BF16, 1536, 1><<<dim3(45, 12), 256, 0, stream>>>(
        h, qkvT + (size_t)i * 1536 * 512, bqkv + i * 1536, qkvb);
    attn_k<<<512, 256, 0, stream>>>(qkvb, x);
    ln_k<<<1440, 256, 0, stream>>>(x, ln2_g + i * 512, ln2_b + i * 512, h);
    gemm_rs<0, 128, 128, 2, 2, 512, ACT_GELU, OUT_BF16, 2048, 1><<<dim3(45, 16), 256, 0, stream>>>(
        h, w1T + (size_t)i * 2048 * 512, b1 + i * 2048, mlph);
    gemm_rs<0, 64, 128, 2, 2, 2048, ACT_NONE, OUT_ATOMIC, 512, 2><<<dim3(90, 4, 2), 256, 0, stream>>>(
        mlph, w2T + (size_t)i * 2048 * 512, b2 + i * 512, x);
  }

  head_k<<<1920, 64, 0, stream>>>(x, lnf_g, lnf_b, whT, out);
}